// Round 1
// baseline (325.799 us; speedup 1.0000x reference)
//
#include <hip/hip_runtime.h>

// PtConv: B=8, N=8192, C_IN=64, C_OUT=128, K=16, M=16, DIM=3
#define BATCH 8
#define NPTS  8192
#define CIN   64
#define COUT  128
#define KNN   16
#define MD    16
#define PTS   16            // points per block
#define DSTRIDE 20          // padded row stride (floats) for s_d
#define AGG_STRIDE 1032     // padded row stride (bf16 elems) for s_agg; 516 dwords == 4 mod 32 -> 2-way LDS aliasing (free)

typedef __attribute__((ext_vector_type(8))) short short8;
typedef __attribute__((ext_vector_type(4))) float f32x4;

__device__ __forceinline__ short f2bf(float f) {
  unsigned u = __float_as_uint(f);
  u = (u + 0x7fffu + ((u >> 16) & 1u)) >> 16;   // round-to-nearest-even
  return (short)u;
}

// Transpose main conv weight [1024,128] -> bf16 [128][1024] in ws; copy output_pts to out tail.
__global__ __launch_bounds__(256) void prep_kernel(
    const float* __restrict__ weight, const float* __restrict__ opts,
    short* __restrict__ Wt, float* __restrict__ out_tail, int do_wt) {
  int tid = blockIdx.x * 256 + threadIdx.x;
  if (do_wt && tid < COUT * CIN * MD) {
    int co = tid >> 10, kk = tid & 1023;
    Wt[tid] = f2bf(weight[(size_t)kk * COUT + co]);
  }
  if (tid < BATCH * NPTS * 3) out_tail[tid] = opts[tid];
}

template <bool USE_WT>
__global__ __launch_bounds__(256, 2) void ptconv_main(
    const float* __restrict__ features, const float* __restrict__ input_pts,
    const float* __restrict__ output_pts, const int* __restrict__ indices,
    const float* __restrict__ centers, const float* __restrict__ weight,
    const float* __restrict__ bias,
    const float* __restrict__ l1_w, const float* __restrict__ l1_b,
    const float* __restrict__ l2_w, const float* __restrict__ l2_b,
    const float* __restrict__ l3_w, const float* __restrict__ l3_b,
    const short* __restrict__ Wt, float* __restrict__ out) {
  __shared__ __align__(16) float s_d[PTS * KNN * DSTRIDE];     // 20.0 KB
  __shared__ __align__(16) short s_agg[PTS * AGG_STRIDE];      // 33.0 KB
  __shared__ int s_idx[PTS * KNN];                             // 1 KB

  const int t = threadIdx.x;
  const int blk = blockIdx.x;          // 4096 blocks
  const int batch = blk >> 9;          // 512 blocks per batch
  const int n0 = (blk & 511) * PTS;

  s_idx[t] = indices[((size_t)batch * NPTS + n0) * KNN + t];   // coalesced, 256 = PTS*KNN
  __syncthreads();

  // ---------- phase 1: per-neighbor MLP (one neighbor per thread) ----------
  // MLP weights are wave-uniform reads -> scalar loads (SMEM pipe), LDS stays free.
  {
    const int pt = t >> 4;
    const int id = s_idx[t];
    const float* op = &output_pts[((size_t)batch * NPTS + n0 + pt) * 3];
    const float* ip = &input_pts[((size_t)batch * NPTS + id) * 3];
    const float px = ip[0] - op[0], py = ip[1] - op[1], pz = ip[2] - op[2];
    float d48[48];
#pragma unroll
    for (int m = 0; m < 16; ++m) {
      d48[m]      = px - centers[m];
      d48[16 + m] = py - centers[16 + m];
      d48[32 + m] = pz - centers[32 + m];
    }
    float h1[32];
#pragma unroll
    for (int o = 0; o < 32; ++o) {
      float a = l1_b[o];
#pragma unroll
      for (int i = 0; i < 48; ++i) a += d48[i] * l1_w[o * 48 + i];
      h1[o] = fmaxf(a, 0.f);
    }
    float h2[16];
#pragma unroll
    for (int o = 0; o < 16; ++o) {
      float a = l2_b[o];
#pragma unroll
      for (int i = 0; i < 32; ++i) a += h1[i] * l2_w[o * 32 + i];
      h2[o] = fmaxf(a, 0.f);
    }
    float h3[16];
#pragma unroll
    for (int o = 0; o < 16; ++o) {
      float a = l3_b[o];
#pragma unroll
      for (int i = 0; i < 16; ++i) a += h2[i] * l3_w[o * 16 + i];
      h3[o] = fmaxf(a, 0.f);
    }
    f32x4* dst = (f32x4*)&s_d[t * DSTRIDE];
    dst[0] = (f32x4){h3[0],  h3[1],  h3[2],  h3[3]};
    dst[1] = (f32x4){h3[4],  h3[5],  h3[6],  h3[7]};
    dst[2] = (f32x4){h3[8],  h3[9],  h3[10], h3[11]};
    dst[3] = (f32x4){h3[12], h3[13], h3[14], h3[15]};
  }
  __syncthreads();

  // ---------- phase 2: agg[pt][c*16+m] = sum_k feats[idx_k][c] * d[k][m] ----------
  // wave w handles pts 4w..4w+3; lane = channel c (coalesced 256B feature reads).
  {
    const int lane = t & 63;
    const int w = t >> 6;
#pragma unroll
    for (int pp = 0; pp < 4; ++pp) {
      const int pt = w * 4 + pp;
      float acc[16];
#pragma unroll
      for (int m = 0; m < 16; ++m) acc[m] = 0.f;
#pragma unroll
      for (int k = 0; k < KNN; ++k) {
        const int id = s_idx[pt * KNN + k];
        const float f = features[((size_t)batch * NPTS + id) * CIN + lane];
        const f32x4* dp = (const f32x4*)&s_d[(pt * KNN + k) * DSTRIDE];
        const f32x4 a0 = dp[0], a1 = dp[1], a2 = dp[2], a3 = dp[3];
        acc[0]  += f * a0[0]; acc[1]  += f * a0[1]; acc[2]  += f * a0[2]; acc[3]  += f * a0[3];
        acc[4]  += f * a1[0]; acc[5]  += f * a1[1]; acc[6]  += f * a1[2]; acc[7]  += f * a1[3];
        acc[8]  += f * a2[0]; acc[9]  += f * a2[1]; acc[10] += f * a2[2]; acc[11] += f * a2[3];
        acc[12] += f * a3[0]; acc[13] += f * a3[1]; acc[14] += f * a3[2]; acc[15] += f * a3[3];
      }
      const int basew = pt * AGG_STRIDE + lane * 16;   // kk = c*16 + m matches weight.reshape order
#pragma unroll
      for (int m = 0; m < 16; ++m) s_agg[basew + m] = f2bf(acc[m]);
    }
  }
  __syncthreads();

  // ---------- phase 3: MFMA GEMM [16 x 1024] @ [1024 x 128] ----------
  // wave w covers cols [32w, 32w+32); A frag shared by both N-tiles.
  {
    const int lane = t & 63;
    const int w = t >> 6;
    const int quad = lane >> 4;
    const int lrow = lane & 15;
    f32x4 acc0 = {0.f, 0.f, 0.f, 0.f};
    f32x4 acc1 = {0.f, 0.f, 0.f, 0.f};
    const int co0 = w * 32 + lrow;
    const int co1 = co0 + 16;
    const short* arow = s_agg + lrow * AGG_STRIDE + quad * 8;
#pragma unroll 4
    for (int kb = 0; kb < 32; ++kb) {
      const short8 a = *(const short8*)(arow + kb * 32);
      short8 b0, b1;
      if (USE_WT) {
        b0 = *(const short8*)(Wt + (size_t)co0 * 1024 + kb * 32 + quad * 8);
        b1 = *(const short8*)(Wt + (size_t)co1 * 1024 + kb * 32 + quad * 8);
      } else {
#pragma unroll
        for (int j = 0; j < 8; ++j) {
          const int kk = kb * 32 + quad * 8 + j;
          b0[j] = f2bf(weight[(size_t)kk * COUT + co0]);
          b1[j] = f2bf(weight[(size_t)kk * COUT + co1]);
        }
      }
      acc0 = __builtin_amdgcn_mfma_f32_16x16x32_bf16(a, b0, acc0, 0, 0, 0);
      acc1 = __builtin_amdgcn_mfma_f32_16x16x32_bf16(a, b1, acc1, 0, 0, 0);
    }
    const float bi0 = bias[co0], bi1 = bias[co1];
#pragma unroll
    for (int r = 0; r < 4; ++r) {
      const int pt = quad * 4 + r;     // D: row = quad*4 + reg, col = lane&15
      const size_t rowo = ((size_t)batch * NPTS + n0 + pt) * COUT;
      out[rowo + co0] = acc0[r] * 0.0625f + bi0;
      out[rowo + co1] = acc1[r] * 0.0625f + bi1;
    }
  }
}

extern "C" void kernel_launch(void* const* d_in, const int* in_sizes, int n_in,
                              void* d_out, int out_size, void* d_ws, size_t ws_size,
                              hipStream_t stream) {
  const float* features   = (const float*)d_in[0];
  const float* input_pts  = (const float*)d_in[1];
  const float* output_pts = (const float*)d_in[2];
  const int*   indices    = (const int*)d_in[3];
  const float* centers    = (const float*)d_in[4];
  const float* weight     = (const float*)d_in[5];
  const float* bias       = (const float*)d_in[6];
  const float* l1_w       = (const float*)d_in[7];
  const float* l1_b       = (const float*)d_in[8];
  const float* l2_w       = (const float*)d_in[9];
  const float* l2_b       = (const float*)d_in[10];
  const float* l3_w       = (const float*)d_in[11];
  const float* l3_b       = (const float*)d_in[12];
  float* out = (float*)d_out;
  short* Wt  = (short*)d_ws;
  const bool use_wt = ws_size >= (size_t)(COUT * CIN * MD) * sizeof(short);

  float* out_tail = out + (size_t)BATCH * NPTS * COUT;
  prep_kernel<<<(BATCH * NPTS * 3 + 255) / 256, 256, 0, stream>>>(
      weight, output_pts, Wt, out_tail, use_wt ? 1 : 0);

  const int grid = (BATCH * NPTS) / PTS;   // 4096
  if (use_wt) {
    ptconv_main<true><<<grid, 256, 0, stream>>>(
        features, input_pts, output_pts, indices, centers, weight, bias,
        l1_w, l1_b, l2_w, l2_b, l3_w, l3_b, Wt, out);
  } else {
    ptconv_main<false><<<grid, 256, 0, stream>>>(
        features, input_pts, output_pts, indices, centers, weight, bias,
        l1_w, l1_b, l2_w, l2_b, l3_w, l3_b, Wt, out);
  }
}

// Round 2
// 281.946 us; speedup vs baseline: 1.1555x; 1.1555x over previous
//
#include <hip/hip_runtime.h>

// PtConv: B=8, N=8192, C_IN=64, C_OUT=128, K=16, M=16, DIM=3
#define BATCH 8
#define NPTS  8192
#define CIN   64
#define COUT  128
#define KNN   16
#define MD    16
#define PTS   16            // points per block
#define DT_STR 264          // s_dT row stride in shorts (132 dw == 4 mod 32 -> 2-way aliasing, free)
#define AGG_STRIDE 1032     // s_agg per-point stride (shorts); 516 dw == 4 mod 32

#define NWT   (COUT * CIN * MD)          // 131072 bf16 elems
#define NFBF  (BATCH * NPTS * CIN)       // 4194304 bf16 elems

typedef __attribute__((ext_vector_type(8))) short short8;
typedef __attribute__((ext_vector_type(4))) short short4v;
typedef __attribute__((ext_vector_type(4))) float f32x4;
typedef __attribute__((ext_vector_type(2))) float f32x2;

__device__ __forceinline__ short f2bf(float f) {
  unsigned u = __float_as_uint(f);
  u = (u + 0x7fffu + ((u >> 16) & 1u)) >> 16;   // round-to-nearest-even
  return (short)u;
}

// prep: Wt = bf16 transpose of weight [128][1024]; fbf = bf16 copy of features; out tail = output_pts.
__global__ __launch_bounds__(256) void prep_kernel(
    const float* __restrict__ weight, const float* __restrict__ opts,
    const float* __restrict__ feats,
    short* __restrict__ Wt, short* __restrict__ fbf,
    float* __restrict__ out_tail, int mode) {
  int tid = blockIdx.x * 256 + threadIdx.x;
  if (mode >= 1 && tid < NWT) {
    int co = tid >> 10, kk = tid & 1023;
    Wt[tid] = f2bf(weight[(size_t)kk * COUT + co]);
  }
  if (mode >= 2 && tid < NFBF) fbf[tid] = f2bf(feats[tid]);
  if (tid < BATCH * NPTS * 3) out_tail[tid] = opts[tid];
}

template <int MODE>
__global__ __launch_bounds__(256, 3) void ptconv_main(
    const float* __restrict__ features, const float* __restrict__ input_pts,
    const float* __restrict__ output_pts, const int* __restrict__ indices,
    const float* __restrict__ centers, const float* __restrict__ weight,
    const float* __restrict__ bias,
    const float* __restrict__ l1_w, const float* __restrict__ l1_b,
    const float* __restrict__ l2_w, const float* __restrict__ l2_b,
    const float* __restrict__ l3_w, const float* __restrict__ l3_b,
    const short* __restrict__ Wt, const short* __restrict__ fbf,
    float* __restrict__ out) {
  __shared__ __align__(16) short s_dT[MD * DT_STR];            // 8448 B  [m][neighbor]
  __shared__ __align__(16) short s_agg[PTS * AGG_STRIDE];      // 33024 B [pt][c*16+m]
  __shared__ __align__(16) int   s_idx[PTS * KNN];             // 1024 B
  // total 42.5 KB -> 3 blocks/CU

  const int t = threadIdx.x;
  const int blk = blockIdx.x;          // 4096 blocks
  const int batch = blk >> 9;
  const int n0 = (blk & 511) * PTS;
  const int lane = t & 63;
  const int wv = t >> 6;
  const int quad = lane >> 4;
  const int lrow = lane & 15;

  s_idx[t] = indices[((size_t)batch * NPTS + n0) * KNN + t];

  // ---------- phase 1: per-neighbor MLP, packed-fp32 VALU ----------
  {
    const int pt = t >> 4;
    const int id = s_idx[t];           // own thread's write; same-wave DS in-order
    const float* op = &output_pts[((size_t)batch * NPTS + n0 + pt) * 3];
    const float* ip = &input_pts[((size_t)batch * NPTS + id) * 3];
    const float px = ip[0] - op[0], py = ip[1] - op[1], pz = ip[2] - op[2];

    f32x2 dv[24];
    {
      const f32x2 px2 = {px, px}, py2 = {py, py}, pz2 = {pz, pz};
      const f32x2* cx = (const f32x2*)centers;
      const f32x2* cy = (const f32x2*)(centers + 16);
      const f32x2* cz = (const f32x2*)(centers + 32);
#pragma unroll
      for (int i = 0; i < 8; ++i) {
        dv[i]      = px2 - cx[i];
        dv[8 + i]  = py2 - cy[i];
        dv[16 + i] = pz2 - cz[i];
      }
    }
    float h1[32];
#pragma unroll
    for (int o = 0; o < 32; ++o) {
      const f32x2* wr = (const f32x2*)(l1_w + o * 48);
      f32x2 acc = {0.f, 0.f};
#pragma unroll
      for (int i = 0; i < 24; ++i) acc += dv[i] * wr[i];
      h1[o] = fmaxf(acc[0] + acc[1] + l1_b[o], 0.f);
    }
    f32x2 h1v[16];
#pragma unroll
    for (int i = 0; i < 16; ++i) h1v[i] = (f32x2){h1[2 * i], h1[2 * i + 1]};
    float h2[16];
#pragma unroll
    for (int o = 0; o < 16; ++o) {
      const f32x2* wr = (const f32x2*)(l2_w + o * 32);
      f32x2 acc = {0.f, 0.f};
#pragma unroll
      for (int i = 0; i < 16; ++i) acc += h1v[i] * wr[i];
      h2[o] = fmaxf(acc[0] + acc[1] + l2_b[o], 0.f);
    }
    f32x2 h2v[8];
#pragma unroll
    for (int i = 0; i < 8; ++i) h2v[i] = (f32x2){h2[2 * i], h2[2 * i + 1]};
#pragma unroll
    for (int o = 0; o < 16; ++o) {
      const f32x2* wr = (const f32x2*)(l3_w + o * 16);
      f32x2 acc = {0.f, 0.f};
#pragma unroll
      for (int i = 0; i < 8; ++i) acc += h2v[i] * wr[i];
      const float h3 = fmaxf(acc[0] + acc[1] + l3_b[o], 0.f);
      s_dT[o * DT_STR + t] = f2bf(h3);     // transposed: [m][neighbor], 2-way banks (free)
    }
  }
  __syncthreads();

  // ---------- phase 2: agg via MFMA 16x16x16 (K = 16 neighbors) ----------
  // D[c_sub][m] = sum_k F^T[c][k] * d[k][m]; A row = c_sub = lrow, B col = m = lrow.
  {
#pragma unroll
    for (int pp = 0; pp < 4; ++pp) {
      const int pt = wv * 4 + pp;
      // B frag: d[k = quad*4+j][m = lrow] -> 4 consecutive shorts in s_dT row lrow
      const short4v bfrag = *(const short4v*)&s_dT[lrow * DT_STR + pt * 16 + quad * 4];
      const int4 idx4 = *(const int4*)&s_idx[pt * 16 + quad * 4];
#pragma unroll
      for (int ct = 0; ct < 4; ++ct) {
        short4v afr;
#pragma unroll
        for (int j = 0; j < 4; ++j) {
          const int id = ((const int*)&idx4)[j];
          const size_t off = ((size_t)batch * NPTS + id) * CIN + ct * 16 + lrow;
          if (MODE >= 2) afr[j] = fbf[off];
          else           afr[j] = f2bf(features[off]);
        }
        f32x4 dd = __builtin_amdgcn_mfma_f32_16x16x16bf16_1k(
            afr, bfrag, (f32x4){0.f, 0.f, 0.f, 0.f}, 0, 0, 0);
        // quad-rotated reg order: the 4 quads land on disjoint 8-dword groups -> conflict-free
#pragma unroll
        for (int r = 0; r < 4; ++r) {
          const int rr = (r + quad) & 3;
          const int c = ct * 16 + quad * 4 + rr;
          s_agg[pt * AGG_STRIDE + c * 16 + lrow] = f2bf(dd[rr]);
        }
      }
    }
  }
  __syncthreads();

  // ---------- phase 3: MFMA GEMM [16 x 1024] @ [1024 x 128] ----------
  {
    f32x4 acc0 = {0.f, 0.f, 0.f, 0.f};
    f32x4 acc1 = {0.f, 0.f, 0.f, 0.f};
    const int co0 = wv * 32 + lrow;
    const int co1 = co0 + 16;
    const short* arow = s_agg + lrow * AGG_STRIDE + quad * 8;
#pragma unroll 4
    for (int kb = 0; kb < 32; ++kb) {
      const short8 a = *(const short8*)(arow + kb * 32);
      short8 b0, b1;
      if (MODE >= 1) {
        b0 = *(const short8*)(Wt + (size_t)co0 * 1024 + kb * 32 + quad * 8);
        b1 = *(const short8*)(Wt + (size_t)co1 * 1024 + kb * 32 + quad * 8);
      } else {
#pragma unroll
        for (int j = 0; j < 8; ++j) {
          const int kk = kb * 32 + quad * 8 + j;
          b0[j] = f2bf(weight[(size_t)kk * COUT + co0]);
          b1[j] = f2bf(weight[(size_t)kk * COUT + co1]);
        }
      }
      acc0 = __builtin_amdgcn_mfma_f32_16x16x32_bf16(a, b0, acc0, 0, 0, 0);
      acc1 = __builtin_amdgcn_mfma_f32_16x16x32_bf16(a, b1, acc1, 0, 0, 0);
    }
    const float bi0 = bias[co0], bi1 = bias[co1];
#pragma unroll
    for (int r = 0; r < 4; ++r) {
      const int pt = quad * 4 + r;     // D: row = quad*4 + reg, col = lane&15
      const size_t rowo = ((size_t)batch * NPTS + n0 + pt) * COUT;
      out[rowo + co0] = acc0[r] * 0.0625f + bi0;
      out[rowo + co1] = acc1[r] * 0.0625f + bi1;
    }
  }
}

extern "C" void kernel_launch(void* const* d_in, const int* in_sizes, int n_in,
                              void* d_out, int out_size, void* d_ws, size_t ws_size,
                              hipStream_t stream) {
  const float* features   = (const float*)d_in[0];
  const float* input_pts  = (const float*)d_in[1];
  const float* output_pts = (const float*)d_in[2];
  const int*   indices    = (const int*)d_in[3];
  const float* centers    = (const float*)d_in[4];
  const float* weight     = (const float*)d_in[5];
  const float* bias       = (const float*)d_in[6];
  const float* l1_w       = (const float*)d_in[7];
  const float* l1_b       = (const float*)d_in[8];
  const float* l2_w       = (const float*)d_in[9];
  const float* l2_b       = (const float*)d_in[10];
  const float* l3_w       = (const float*)d_in[11];
  const float* l3_b       = (const float*)d_in[12];
  float* out = (float*)d_out;
  short* Wt  = (short*)d_ws;
  short* fbf = (short*)d_ws + NWT;

  int mode = 0;
  if (ws_size >= (size_t)NWT * 2) mode = 1;
  if (ws_size >= (size_t)NWT * 2 + (size_t)NFBF * 2) mode = 2;

  float* out_tail = out + (size_t)BATCH * NPTS * COUT;
  const int prep_elems = (mode >= 2) ? NFBF : BATCH * NPTS * 3;
  prep_kernel<<<(prep_elems + 255) / 256, 256, 0, stream>>>(
      weight, output_pts, features, Wt, fbf, out_tail, mode);

  const int grid = (BATCH * NPTS) / PTS;   // 4096
  if (mode >= 2) {
    ptconv_main<2><<<grid, 256, 0, stream>>>(
        features, input_pts, output_pts, indices, centers, weight, bias,
        l1_w, l1_b, l2_w, l2_b, l3_w, l3_b, Wt, fbf, out);
  } else if (mode == 1) {
    ptconv_main<1><<<grid, 256, 0, stream>>>(
        features, input_pts, output_pts, indices, centers, weight, bias,
        l1_w, l1_b, l2_w, l2_b, l3_w, l3_b, Wt, fbf, out);
  } else {
    ptconv_main<0><<<grid, 256, 0, stream>>>(
        features, input_pts, output_pts, indices, centers, weight, bias,
        l1_w, l1_b, l2_w, l2_b, l3_w, l3_b, Wt, fbf, out);
  }
}

// Round 3
// 247.111 us; speedup vs baseline: 1.3184x; 1.1410x over previous
//
#include <hip/hip_runtime.h>

// PtConv: B=8, N=8192, C_IN=64, C_OUT=128, K=16, M=16, DIM=3
#define BATCH 8
#define NPTS  8192
#define CIN   64
#define COUT  128
#define KNN   16
#define MD    16
#define PTS   16            // points per block (conv kernel)
#define DT_STR 264          // fallback mono kernel only
#define AGG_STRIDE 1032     // s_agg per-point stride (shorts); 516 dw == 4 mod 32

#define NWT    (COUT * CIN * MD)          // 131072 bf16
#define NFBF   (BATCH * NPTS * CIN)       // 4194304 bf16
#define NPTS_G (BATCH * NPTS)             // 65536
#define NNBR   (NPTS_G * KNN)             // 1048576

typedef __attribute__((ext_vector_type(8))) short short8;
typedef __attribute__((ext_vector_type(4))) short short4v;
typedef __attribute__((ext_vector_type(4))) float f32x4;
typedef __attribute__((ext_vector_type(2))) float f32x2;

__device__ __forceinline__ short f2bf(float f) {
  unsigned u = __float_as_uint(f);
  u = (u + 0x7fffu + ((u >> 16) & 1u)) >> 16;   // RNE
  return (short)u;
}

// prep: Wt (bf16, transposed, k-permuted in mode 3); fbf (bf16 features);
//       Gc = collapsed layer-1 (G[32][3], c0[32]); out tail = output_pts copy.
__global__ __launch_bounds__(256) void prep_kernel(
    const float* __restrict__ weight, const float* __restrict__ opts,
    const float* __restrict__ feats, const float* __restrict__ centers,
    const float* __restrict__ l1_w, const float* __restrict__ l1_b,
    short* __restrict__ Wt, short* __restrict__ fbf, float* __restrict__ Gc,
    float* __restrict__ out_tail, int mode) {
  int tid = blockIdx.x * 256 + threadIdx.x;
  if (mode >= 1 && tid < NWT) {
    int co = tid >> 10, o = tid & 1023;
    int k;
    if (mode == 3) {  // k(o): swap the q and r bit-fields (see conv_kernel s_agg layout)
      int m = o & 15, q = (o >> 4) & 3, r = (o >> 6) & 3, ct = o >> 8;
      k = ct * 256 + q * 64 + r * 16 + m;
    } else {
      k = o;
    }
    Wt[tid] = f2bf(weight[(size_t)k * COUT + co]);
  }
  if (mode >= 2 && tid < NFBF) fbf[tid] = f2bf(feats[tid]);
  if (mode == 3 && tid < 32) {
    float g0 = 0.f, g1 = 0.f, g2 = 0.f, cc = l1_b[tid];
    const float* wr = l1_w + tid * 48;
#pragma unroll
    for (int m = 0; m < 16; ++m) {
      g0 += wr[m]; g1 += wr[16 + m]; g2 += wr[32 + m];
    }
#pragma unroll
    for (int i = 0; i < 48; ++i) cc -= wr[i] * centers[i];
    Gc[tid * 3 + 0] = g0; Gc[tid * 3 + 1] = g1; Gc[tid * 3 + 2] = g2;
    Gc[96 + tid] = cc;
  }
  if (tid < BATCH * NPTS * 3) out_tail[tid] = opts[tid];
}

// kernel A: one thread per (point, neighbor). MLP with collapsed layer 1.
// Writes d/16 as bf16, transposed per point: dws[ptg*256 + m*16 + k].
__global__ __launch_bounds__(256, 4) void mlp_kernel(
    const int* __restrict__ indices, const float* __restrict__ input_pts,
    const float* __restrict__ output_pts, const float* __restrict__ Gc,
    const float* __restrict__ l2_w, const float* __restrict__ l2_b,
    const float* __restrict__ l3_w, const float* __restrict__ l3_b,
    short* __restrict__ dws) {
  const int nbr = blockIdx.x * 256 + threadIdx.x;   // < NNBR
  const int ptg = nbr >> 4, kk = nbr & 15;
  const int batch = ptg >> 13;
  const int id = indices[nbr];
  const float* op = output_pts + (size_t)ptg * 3;
  const float* ip = input_pts + ((size_t)(batch << 13) + id) * 3;
  const float px = ip[0] - op[0], py = ip[1] - op[1], pz = ip[2] - op[2];

  float h1[32];
#pragma unroll
  for (int o = 0; o < 32; ++o)
    h1[o] = fmaxf(Gc[o * 3] * px + Gc[o * 3 + 1] * py + Gc[o * 3 + 2] * pz + Gc[96 + o], 0.f);
  f32x2 h1v[16];
#pragma unroll
  for (int i = 0; i < 16; ++i) h1v[i] = (f32x2){h1[2 * i], h1[2 * i + 1]};
  float h2[16];
#pragma unroll
  for (int o = 0; o < 16; ++o) {
    const f32x2* wr = (const f32x2*)(l2_w + o * 32);
    f32x2 acc = {0.f, 0.f};
#pragma unroll
    for (int i = 0; i < 16; ++i) acc += h1v[i] * wr[i];
    h2[o] = fmaxf(acc[0] + acc[1] + l2_b[o], 0.f);
  }
  f32x2 h2v[8];
#pragma unroll
  for (int i = 0; i < 8; ++i) h2v[i] = (f32x2){h2[2 * i], h2[2 * i + 1]};
  short* dst = dws + (size_t)ptg * 256 + kk;
#pragma unroll
  for (int o = 0; o < 16; ++o) {
    const f32x2* wr = (const f32x2*)(l3_w + o * 16);
    f32x2 acc = {0.f, 0.f};
#pragma unroll
    for (int i = 0; i < 8; ++i) acc += h2v[i] * wr[i];
    const float h3 = fmaxf(acc[0] + acc[1] + l3_b[o], 0.f) * 0.0625f;  // fold /K
    dst[o * 16] = f2bf(h3);
  }
}

// kernel B: gather + agg-MFMA + output GEMM.
// s_agg k-slot layout: o = (ct*4+r)*64 + quad*16 + m holds logical k = ct*256+q*64+r*16+m
// (matches Wt's k(o) permutation; phase-2 stores hit all 32 banks 2-way = free).
__global__ __launch_bounds__(256, 4) void conv_kernel(
    const int* __restrict__ indices, const short* __restrict__ fbf,
    const short* __restrict__ dws, const short* __restrict__ Wt,
    const float* __restrict__ bias, float* __restrict__ out) {
  __shared__ __align__(16) short s_agg[PTS * AGG_STRIDE];   // 33024 B
  __shared__ __align__(16) int   s_idx[PTS * KNN];          // 1024 B -> 4 blocks/CU

  const int t = threadIdx.x, blk = blockIdx.x;              // 4096 blocks
  const int batch = blk >> 9, n0 = (blk & 511) * PTS;
  const int lane = t & 63, wv = t >> 6, quad = lane >> 4, lrow = lane & 15;

  s_idx[t] = indices[((size_t)(batch * NPTS + n0)) * KNN + t];
  __syncthreads();

  // ---------- phase 2: agg via MFMA 16x16x16 (contract K = 16 neighbors) ----------
#pragma unroll
  for (int pp = 0; pp < 4; ++pp) {
    const int pt = wv * 4 + pp;
    const int ptg = batch * NPTS + n0 + pt;
    // B frag: d[k=quad*4+j][m=lrow] -> b64 from transposed dws
    const short4v bfrag = *(const short4v*)(dws + (size_t)ptg * 256 + lrow * 16 + quad * 4);
    const int4 idx4 = *(const int4*)&s_idx[pt * KNN + quad * 4];
    const int ids[4] = {idx4.x, idx4.y, idx4.z, idx4.w};
    short fr[4][4];
#pragma unroll
    for (int j = 0; j < 4; ++j) {
      const short* fp = fbf + ((size_t)(batch * NPTS) + ids[j]) * CIN + lrow;
#pragma unroll
      for (int ct = 0; ct < 4; ++ct) fr[ct][j] = fp[ct * 16];
    }
#pragma unroll
    for (int ct = 0; ct < 4; ++ct) {
      const short4v afr = {fr[ct][0], fr[ct][1], fr[ct][2], fr[ct][3]};
      const f32x4 dd = __builtin_amdgcn_mfma_f32_16x16x16bf16_1k(
          afr, bfrag, (f32x4){0.f, 0.f, 0.f, 0.f}, 0, 0, 0);
#pragma unroll
      for (int r = 0; r < 4; ++r)   // D: row(c_sub)=quad*4+r, col(m)=lrow
        s_agg[pt * AGG_STRIDE + (ct * 4 + r) * 64 + quad * 16 + lrow] = f2bf(dd[r]);
    }
  }
  __syncthreads();

  // ---------- phase 3: MFMA GEMM [16 x 1024] @ [1024 x 128] ----------
  f32x4 acc0 = {0.f, 0.f, 0.f, 0.f};
  f32x4 acc1 = {0.f, 0.f, 0.f, 0.f};
  const int co0 = wv * 32 + lrow, co1 = co0 + 16;
  const short* arow = s_agg + lrow * AGG_STRIDE + quad * 8;
  const short* wp0 = Wt + ((size_t)co0 << 10) + quad * 8;
  const short* wp1 = Wt + ((size_t)co1 << 10) + quad * 8;
#pragma unroll 8
  for (int kb = 0; kb < 32; ++kb) {
    const short8 a  = *(const short8*)(arow + kb * 32);
    const short8 b0 = *(const short8*)(wp0 + kb * 32);
    const short8 b1 = *(const short8*)(wp1 + kb * 32);
    acc0 = __builtin_amdgcn_mfma_f32_16x16x32_bf16(a, b0, acc0, 0, 0, 0);
    acc1 = __builtin_amdgcn_mfma_f32_16x16x32_bf16(a, b1, acc1, 0, 0, 0);
  }
  const float bi0 = bias[co0], bi1 = bias[co1];
#pragma unroll
  for (int r = 0; r < 4; ++r) {
    const int pt = quad * 4 + r;                 // D: row=quad*4+reg, col=lane&15
    const size_t rowo = ((size_t)(batch * NPTS + n0 + pt)) * COUT;
    out[rowo + co0] = acc0[r] + bi0;             // /K already folded into d
    out[rowo + co1] = acc1[r] + bi1;
  }
}

// ---------------- fallback monolithic kernel (R2), for small workspace ----------------
template <int MODE>
__global__ __launch_bounds__(256, 3) void ptconv_mono(
    const float* __restrict__ features, const float* __restrict__ input_pts,
    const float* __restrict__ output_pts, const int* __restrict__ indices,
    const float* __restrict__ centers, const float* __restrict__ weight,
    const float* __restrict__ bias,
    const float* __restrict__ l1_w, const float* __restrict__ l1_b,
    const float* __restrict__ l2_w, const float* __restrict__ l2_b,
    const float* __restrict__ l3_w, const float* __restrict__ l3_b,
    const short* __restrict__ Wt, const short* __restrict__ fbf,
    float* __restrict__ out) {
  __shared__ __align__(16) short s_dT[MD * DT_STR];
  __shared__ __align__(16) short s_agg[PTS * AGG_STRIDE];
  __shared__ __align__(16) int   s_idx[PTS * KNN];

  const int t = threadIdx.x;
  const int blk = blockIdx.x;
  const int batch = blk >> 9;
  const int n0 = (blk & 511) * PTS;
  const int lane = t & 63;
  const int wv = t >> 6;
  const int quad = lane >> 4;
  const int lrow = lane & 15;

  s_idx[t] = indices[((size_t)batch * NPTS + n0) * KNN + t];
  {
    const int pt = t >> 4;
    const int id = s_idx[t];
    const float* op = &output_pts[((size_t)batch * NPTS + n0 + pt) * 3];
    const float* ip = &input_pts[((size_t)batch * NPTS + id) * 3];
    const float px = ip[0] - op[0], py = ip[1] - op[1], pz = ip[2] - op[2];
    f32x2 dv[24];
    {
      const f32x2 px2 = {px, px}, py2 = {py, py}, pz2 = {pz, pz};
      const f32x2* cx = (const f32x2*)centers;
      const f32x2* cy = (const f32x2*)(centers + 16);
      const f32x2* cz = (const f32x2*)(centers + 32);
#pragma unroll
      for (int i = 0; i < 8; ++i) {
        dv[i] = px2 - cx[i]; dv[8 + i] = py2 - cy[i]; dv[16 + i] = pz2 - cz[i];
      }
    }
    float h1[32];
#pragma unroll
    for (int o = 0; o < 32; ++o) {
      const f32x2* wr = (const f32x2*)(l1_w + o * 48);
      f32x2 acc = {0.f, 0.f};
#pragma unroll
      for (int i = 0; i < 24; ++i) acc += dv[i] * wr[i];
      h1[o] = fmaxf(acc[0] + acc[1] + l1_b[o], 0.f);
    }
    f32x2 h1v[16];
#pragma unroll
    for (int i = 0; i < 16; ++i) h1v[i] = (f32x2){h1[2 * i], h1[2 * i + 1]};
    float h2[16];
#pragma unroll
    for (int o = 0; o < 16; ++o) {
      const f32x2* wr = (const f32x2*)(l2_w + o * 32);
      f32x2 acc = {0.f, 0.f};
#pragma unroll
      for (int i = 0; i < 16; ++i) acc += h1v[i] * wr[i];
      h2[o] = fmaxf(acc[0] + acc[1] + l2_b[o], 0.f);
    }
    f32x2 h2v[8];
#pragma unroll
    for (int i = 0; i < 8; ++i) h2v[i] = (f32x2){h2[2 * i], h2[2 * i + 1]};
#pragma unroll
    for (int o = 0; o < 16; ++o) {
      const f32x2* wr = (const f32x2*)(l3_w + o * 16);
      f32x2 acc = {0.f, 0.f};
#pragma unroll
      for (int i = 0; i < 8; ++i) acc += h2v[i] * wr[i];
      s_dT[o * DT_STR + t] = f2bf(fmaxf(acc[0] + acc[1] + l3_b[o], 0.f));
    }
  }
  __syncthreads();
  {
#pragma unroll
    for (int pp = 0; pp < 4; ++pp) {
      const int pt = wv * 4 + pp;
      const short4v bfrag = *(const short4v*)&s_dT[lrow * DT_STR + pt * 16 + quad * 4];
      const int4 idx4 = *(const int4*)&s_idx[pt * 16 + quad * 4];
#pragma unroll
      for (int ct = 0; ct < 4; ++ct) {
        short4v afr;
#pragma unroll
        for (int j = 0; j < 4; ++j) {
          const int id = ((const int*)&idx4)[j];
          const size_t off = ((size_t)batch * NPTS + id) * CIN + ct * 16 + lrow;
          if (MODE >= 2) afr[j] = fbf[off];
          else           afr[j] = f2bf(features[off]);
        }
        f32x4 dd = __builtin_amdgcn_mfma_f32_16x16x16bf16_1k(
            afr, bfrag, (f32x4){0.f, 0.f, 0.f, 0.f}, 0, 0, 0);
#pragma unroll
        for (int r = 0; r < 4; ++r) {
          const int rr = (r + quad) & 3;
          const int c = ct * 16 + quad * 4 + rr;
          s_agg[pt * AGG_STRIDE + c * 16 + lrow] = f2bf(dd[rr]);
        }
      }
    }
  }
  __syncthreads();
  {
    f32x4 acc0 = {0.f, 0.f, 0.f, 0.f};
    f32x4 acc1 = {0.f, 0.f, 0.f, 0.f};
    const int co0 = wv * 32 + lrow;
    const int co1 = co0 + 16;
    const short* arow = s_agg + lrow * AGG_STRIDE + quad * 8;
#pragma unroll 4
    for (int kb = 0; kb < 32; ++kb) {
      const short8 a = *(const short8*)(arow + kb * 32);
      short8 b0, b1;
      if (MODE >= 1) {
        b0 = *(const short8*)(Wt + (size_t)co0 * 1024 + kb * 32 + quad * 8);
        b1 = *(const short8*)(Wt + (size_t)co1 * 1024 + kb * 32 + quad * 8);
      } else {
#pragma unroll
        for (int j = 0; j < 8; ++j) {
          const int kk = kb * 32 + quad * 8 + j;
          b0[j] = f2bf(weight[(size_t)kk * COUT + co0]);
          b1[j] = f2bf(weight[(size_t)kk * COUT + co1]);
        }
      }
      acc0 = __builtin_amdgcn_mfma_f32_16x16x32_bf16(a, b0, acc0, 0, 0, 0);
      acc1 = __builtin_amdgcn_mfma_f32_16x16x32_bf16(a, b1, acc1, 0, 0, 0);
    }
    const float bi0 = bias[co0], bi1 = bias[co1];
#pragma unroll
    for (int r = 0; r < 4; ++r) {
      const int pt = quad * 4 + r;
      const size_t rowo = ((size_t)batch * NPTS + n0 + pt) * COUT;
      out[rowo + co0] = acc0[r] * 0.0625f + bi0;
      out[rowo + co1] = acc1[r] * 0.0625f + bi1;
    }
  }
}

extern "C" void kernel_launch(void* const* d_in, const int* in_sizes, int n_in,
                              void* d_out, int out_size, void* d_ws, size_t ws_size,
                              hipStream_t stream) {
  const float* features   = (const float*)d_in[0];
  const float* input_pts  = (const float*)d_in[1];
  const float* output_pts = (const float*)d_in[2];
  const int*   indices    = (const int*)d_in[3];
  const float* centers    = (const float*)d_in[4];
  const float* weight     = (const float*)d_in[5];
  const float* bias       = (const float*)d_in[6];
  const float* l1_w       = (const float*)d_in[7];
  const float* l1_b       = (const float*)d_in[8];
  const float* l2_w       = (const float*)d_in[9];
  const float* l2_b       = (const float*)d_in[10];
  const float* l3_w       = (const float*)d_in[11];
  const float* l3_b       = (const float*)d_in[12];
  float* out = (float*)d_out;

  short* Wt  = (short*)d_ws;
  short* fbf = (short*)d_ws + NWT;
  const size_t gc_off = (size_t)(NWT + NFBF) * 2;          // bytes
  float* Gc  = (float*)((char*)d_ws + gc_off);             // 128 floats
  short* dws = (short*)((char*)d_ws + gc_off + 512);
  const size_t need3 = gc_off + 512 + (size_t)NPTS_G * 256 * 2;   // ~42.2 MB

  int mode = 0;
  if (ws_size >= need3) mode = 3;
  else if (ws_size >= (size_t)(NWT + NFBF) * 2) mode = 2;
  else if (ws_size >= (size_t)NWT * 2) mode = 1;

  float* out_tail = out + (size_t)BATCH * NPTS * COUT;
  const int prep_elems = (mode >= 2) ? NFBF : BATCH * NPTS * 3;
  prep_kernel<<<(prep_elems + 255) / 256, 256, 0, stream>>>(
      weight, output_pts, features, centers, l1_w, l1_b, Wt, fbf, Gc, out_tail, mode);

  if (mode == 3) {
    mlp_kernel<<<NNBR / 256, 256, 0, stream>>>(
        indices, input_pts, output_pts, Gc, l2_w, l2_b, l3_w, l3_b, dws);
    conv_kernel<<<NPTS_G / PTS, 256, 0, stream>>>(indices, fbf, dws, Wt, bias, out);
  } else {
    const int grid = NPTS_G / PTS;
    if (mode == 2)
      ptconv_mono<2><<<grid, 256, 0, stream>>>(features, input_pts, output_pts, indices,
          centers, weight, bias, l1_w, l1_b, l2_w, l2_b, l3_w, l3_b, Wt, fbf, out);
    else if (mode == 1)
      ptconv_mono<1><<<grid, 256, 0, stream>>>(features, input_pts, output_pts, indices,
          centers, weight, bias, l1_w, l1_b, l2_w, l2_b, l3_w, l3_b, Wt, fbf, out);
    else
      ptconv_mono<0><<<grid, 256, 0, stream>>>(features, input_pts, output_pts, indices,
          centers, weight, bias, l1_w, l1_b, l2_w, l2_b, l3_w, l3_b, Wt, fbf, out);
  }
}